// Round 1
// baseline (11312.067 us; speedup 1.0000x reference)
//
#include <hip/hip_runtime.h>
#include <hip/hip_fp16.h>

typedef unsigned int uint32;
typedef __attribute__((ext_vector_type(8))) _Float16 half8;
typedef __attribute__((ext_vector_type(4))) float f32x4;

#define T_STEPS 512
#define BSZ 128
#define ISZ 256
#define HSZ 512
#define K1  768            // H + I, concat order (h, x)
#define NG  8              // batch groups
#define BG  16             // batch rows per group
#define GC  32             // workgroups per group (column partition)
#define NC  16             // H-columns per workgroup
#define LDK 776            // padded K stride in fp16 elements (768 + 8 -> 2-way-free LDS banks)

// LDS layout (bytes)
#define LDS_A   0                  // A tile [16][LDK] fp16 (h|x or rh|x)
#define LDS_WZ  24832
#define LDS_WR  49664
#define LDS_WH  74496
#define LDS_SC  99328              // scratch [4][16][17] fp32
#define SMEM_BYTES 103680

__device__ __forceinline__ float sigm(float x) {
  float e = __expf(-fabsf(x));
  float s = 1.f / (1.f + e);
  return x >= 0.f ? s : 1.f - s;
}
__device__ __forceinline__ float tanhx(float x) {
  float e = __expf(-2.f * fabsf(x));
  float t = (1.f - e) / (1.f + e);
  return x >= 0.f ? t : -t;
}
__device__ __forceinline__ uint32 f2x(float a, float b) {
  __half2 t = __floats2half2_rn(a, b);
  return *reinterpret_cast<uint32*>(&t);
}

__global__ __launch_bounds__(256, 1)
void gru_persist(const float* __restrict__ x,
                 const float* __restrict__ Wz, const float* __restrict__ bz,
                 const float* __restrict__ Wr, const float* __restrict__ br,
                 const float* __restrict__ Wh, const float* __restrict__ bh,
                 float* __restrict__ out,
                 unsigned short* h_buf, unsigned short* rh_buf, uint32* flags)
{
  extern __shared__ char smem[];
  _Float16* A_l  = (_Float16*)(smem + LDS_A);
  _Float16* Wz_l = (_Float16*)(smem + LDS_WZ);
  _Float16* Wr_l = (_Float16*)(smem + LDS_WR);
  _Float16* Wh_l = (_Float16*)(smem + LDS_WH);
  float*    sc   = (float*)(smem + LDS_SC);      // [4][16*17]

  const int tid  = threadIdx.x;
  const int g    = blockIdx.x & 7;    // group; blockIdx%8 tends to co-locate a group on one XCD
  const int rank = blockIdx.x >> 3;   // 0..31, owns H cols [rank*16, rank*16+16)
  uint32* gf = flags + g * GC;

  // ---- one-time: load this wg's weight slices into LDS as fp16 ----
  {
    const int r  = tid & 15;          // row within slice
    const int ch = tid >> 4;          // 48-float chunk 0..15
    for (int mi = 0; mi < 3; ++mi) {
      const float* Ws = (mi == 0) ? Wz : (mi == 1 ? Wr : Wh);
      _Float16*    Ld = (mi == 0) ? Wz_l : (mi == 1 ? Wr_l : Wh_l);
      const float4* s = (const float4*)(Ws + (size_t)(rank * NC + r) * K1 + ch * 48);
      uint4* d = (uint4*)(Ld + r * LDK + ch * 48);
      #pragma unroll
      for (int j = 0; j < 6; ++j) {
        float4 v0 = s[2 * j], v1 = s[2 * j + 1];
        d[j] = make_uint4(f2x(v0.x, v0.y), f2x(v0.z, v0.w),
                          f2x(v1.x, v1.y), f2x(v1.z, v1.w));
      }
    }
  }

  const int cl = tid & 15, bl = tid >> 4;      // elementwise mapping: thread -> (batch bl, col cl)
  const int cg = rank * NC + cl;               // global H column
  const int bg = g * BG + bl;                  // global batch row
  const float bz_r = bz[cg], br_r = br[cg], bh_r = bh[cg];

  float h_reg = 0.f;                           // own h[bl][cl], fp32
  float zg = 0.f;

  // prefetch x[0] slice: thread covers row bl, cols cl*16..+16 of I=256
  float4 px0, px1, px2, px3;
  {
    const float4* xs = (const float4*)(x + ((size_t)bg) * ISZ + cl * 16);
    px0 = xs[0]; px1 = xs[1]; px2 = xs[2]; px3 = xs[3];
  }

  const int wv = tid >> 6, lane = tid & 63;
  const int mrow = lane & 15, q = lane >> 4;   // MFMA input row + quad
  const int scO = bl * 17 + cl;

  uint32 bar = 0;

  for (int t = 0; t < T_STEPS; ++t) {
    // ---------- phase 1: stage A = [h | x] ----------
    {
      uint4* xd = (uint4*)(A_l + bl * LDK + HSZ + cl * 16);
      xd[0] = make_uint4(f2x(px0.x, px0.y), f2x(px0.z, px0.w),
                         f2x(px1.x, px1.y), f2x(px1.z, px1.w));
      xd[1] = make_uint4(f2x(px2.x, px2.y), f2x(px2.z, px2.w),
                         f2x(px3.x, px3.y), f2x(px3.z, px3.w));
      const uint4* hs = (const uint4*)(h_buf + (size_t)g * BG * HSZ) + (bl * HSZ + cl * 32) / 8;
      uint4* hd = (uint4*)(A_l + bl * LDK + cl * 32);
      uint4 h0 = hs[0], h1 = hs[1], h2 = hs[2], h3 = hs[3];
      hd[0] = h0; hd[1] = h1; hd[2] = h2; hd[3] = h3;
    }
    __syncthreads();
    // ---------- phase 1 GEMM: z (waves 0,1) and r (waves 2,3), K split 384+384 ----------
    {
      const _Float16* Wt = (wv < 2) ? Wz_l : Wr_l;
      const int kb = (wv & 1) * 384;
      const half8* Ap = (const half8*)(A_l + mrow * LDK + kb + q * 8);
      const half8* Bp = (const half8*)(Wt  + mrow * LDK + kb + q * 8);
      f32x4 acc = {0.f, 0.f, 0.f, 0.f};
      #pragma unroll
      for (int kk = 0; kk < 12; ++kk)
        acc = __builtin_amdgcn_mfma_f32_16x16x32_f16(Ap[kk * 4], Bp[kk * 4], acc, 0, 0, 0);
      float* scw = sc + wv * 272;
      #pragma unroll
      for (int i = 0; i < 4; ++i) scw[(q * 4 + i) * 17 + mrow] = acc[i];  // D: row=q*4+reg, col=lane&15
    }
    __syncthreads();
    {
      float zp = sc[scO] + sc[272 + scO] + bz_r;
      float rp = sc[544 + scO] + sc[816 + scO] + br_r;
      zg = sigm(zp);
      float rg = sigm(rp);
      float rhv = rg * h_reg;
      __half hh = __float2half(rhv);
      uint32 lo = (uint32)__half_as_ushort(hh);
      uint32 hi = (uint32)__shfl_down((int)lo, 1);
      if (!(tid & 1))
        *((uint32*)(rh_buf + (size_t)g * BG * HSZ + bl * HSZ + rank * NC + cl)) = lo | (hi << 16);
    }
    // ---------- group barrier (mid-step) ----------
    ++bar;
    __syncthreads();
    if (tid == 0)
      __hip_atomic_store(gf + rank, bar, __ATOMIC_RELEASE, __HIP_MEMORY_SCOPE_AGENT);
    if (tid < GC)
      while (__hip_atomic_load(gf + tid, __ATOMIC_RELAXED, __HIP_MEMORY_SCOPE_AGENT) < bar) {}
    if (tid < 64) __threadfence();   // acquire: invalidate stale L1/L2 before reading rh_buf
    __syncthreads();
    // ---------- phase 2: stage A = [rh | x], prefetch x[t+1] ----------
    {
      const uint4* rs = (const uint4*)(rh_buf + (size_t)g * BG * HSZ) + (bl * HSZ + cl * 32) / 8;
      uint4* rd = (uint4*)(A_l + bl * LDK + cl * 32);
      uint4 r0 = rs[0], r1 = rs[1], r2 = rs[2], r3 = rs[3];
      rd[0] = r0; rd[1] = r1; rd[2] = r2; rd[3] = r3;
      if (t + 1 < T_STEPS) {
        const float4* xs = (const float4*)(x + ((size_t)(t + 1) * BSZ + bg) * ISZ + cl * 16);
        px0 = xs[0]; px1 = xs[1]; px2 = xs[2]; px3 = xs[3];
      }
    }
    __syncthreads();
    // ---------- phase 2 GEMM: cand, 4-way K split ----------
    {
      const int kb = wv * 192;
      const half8* Ap = (const half8*)(A_l  + mrow * LDK + kb + q * 8);
      const half8* Bp = (const half8*)(Wh_l + mrow * LDK + kb + q * 8);
      f32x4 acc = {0.f, 0.f, 0.f, 0.f};
      #pragma unroll
      for (int kk = 0; kk < 6; ++kk)
        acc = __builtin_amdgcn_mfma_f32_16x16x32_f16(Ap[kk * 4], Bp[kk * 4], acc, 0, 0, 0);
      float* scw = sc + wv * 272;
      #pragma unroll
      for (int i = 0; i < 4; ++i) scw[(q * 4 + i) * 17 + mrow] = acc[i];
    }
    __syncthreads();
    {
      float cp = sc[scO] + sc[272 + scO] + sc[544 + scO] + sc[816 + scO] + bh_r;
      float cand = tanhx(cp);
      float hn = (1.f - zg) * h_reg + zg * cand;
      h_reg = hn;
      out[((size_t)t * BSZ + bg) * HSZ + cg] = hn;
      if (t == T_STEPS - 1)
        out[((size_t)T_STEPS * BSZ + bg) * HSZ + cg] = hn;   // h_last
      __half hh = __float2half(hn);
      uint32 lo = (uint32)__half_as_ushort(hh);
      uint32 hi = (uint32)__shfl_down((int)lo, 1);
      if (!(tid & 1))
        *((uint32*)(h_buf + (size_t)g * BG * HSZ + bl * HSZ + rank * NC + cl)) = lo | (hi << 16);
    }
    // ---------- group barrier (end-of-step) ----------
    ++bar;
    __syncthreads();
    if (tid == 0)
      __hip_atomic_store(gf + rank, bar, __ATOMIC_RELEASE, __HIP_MEMORY_SCOPE_AGENT);
    if (tid < GC)
      while (__hip_atomic_load(gf + tid, __ATOMIC_RELAXED, __HIP_MEMORY_SCOPE_AGENT) < bar) {}
    if (tid < 64) __threadfence();
    __syncthreads();
  }
}

extern "C" void kernel_launch(void* const* d_in, const int* in_sizes, int n_in,
                              void* d_out, int out_size, void* d_ws, size_t ws_size,
                              hipStream_t stream) {
  const float* x  = (const float*)d_in[0];
  const float* Wz = (const float*)d_in[1];
  const float* bz = (const float*)d_in[2];
  const float* Wr = (const float*)d_in[3];
  const float* br = (const float*)d_in[4];
  const float* Wh = (const float*)d_in[5];
  const float* bh = (const float*)d_in[6];
  float* out = (float*)d_out;

  unsigned short* h_buf  = (unsigned short*)d_ws;                  // [8][16][512] fp16
  unsigned short* rh_buf = h_buf + NG * BG * HSZ;                  // [8][16][512] fp16
  uint32* flags = (uint32*)(rh_buf + NG * BG * HSZ);               // [8][32]
  size_t clr_bytes = (size_t)NG * BG * HSZ * 2 * 2 + NG * GC * 4;  // h_buf + rh_buf + flags

  // h0 = 0 and flags = 0 (ws is poisoned 0xAA before every timed launch)
  hipMemsetAsync(d_ws, 0, clr_bytes, stream);

  hipFuncSetAttribute(reinterpret_cast<const void*>(gru_persist),
                      hipFuncAttributeMaxDynamicSharedMemorySize, SMEM_BYTES);

  hipLaunchKernelGGL(gru_persist, dim3(NG * GC), dim3(256), SMEM_BYTES, stream,
                     x, Wz, bz, Wr, br, Wh, bh, out, h_buf, rh_buf, flags);
}

// Round 2
// 3338.882 us; speedup vs baseline: 3.3880x; 3.3880x over previous
//
#include <hip/hip_runtime.h>
#include <hip/hip_fp16.h>

typedef unsigned int uint32;
typedef unsigned long long uint64;
typedef __attribute__((ext_vector_type(8))) _Float16 half8;
typedef __attribute__((ext_vector_type(4))) float f32x4;

#define T_STEPS 512
#define BSZ 128
#define ISZ 256
#define HSZ 512
#define K1  768            // H + I, concat order (h, x)
#define NG  8              // batch groups
#define BG  16             // batch rows per group
#define GC  32             // workgroups per group (column partition)
#define NC  16             // H-columns per workgroup
#define LDK 776            // padded K stride (fp16 elems)

// LDS layout (bytes)
#define LDS_A   0                  // A tile [16][LDK] fp16
#define LDS_WZ  24832
#define LDS_WR  49664
#define LDS_WH  74496
#define LDS_SC  99328              // scratch [4][16][17] fp32
#define SMEM_BYTES 103680

// relaxed agent-scope atomics: per-access coherence (sc1), NO buffer_wbl2/inv
#define AST(p, v) __hip_atomic_store((p), (v), __ATOMIC_RELAXED, __HIP_MEMORY_SCOPE_AGENT)
#define ALD(p)    __hip_atomic_load((p), __ATOMIC_RELAXED, __HIP_MEMORY_SCOPE_AGENT)

__device__ __forceinline__ float sigm(float x) {
  float e = __expf(-fabsf(x));
  float s = 1.f / (1.f + e);
  return x >= 0.f ? s : 1.f - s;
}
__device__ __forceinline__ float tanhx(float x) {
  float e = __expf(-2.f * fabsf(x));
  float t = (1.f - e) / (1.f + e);
  return x >= 0.f ? t : -t;
}
__device__ __forceinline__ uint32 f2x(float a, float b) {
  __half2 t = __floats2half2_rn(a, b);
  return *reinterpret_cast<uint32*>(&t);
}

__global__ __launch_bounds__(256, 1)
void gru_persist(const float* __restrict__ x,
                 const float* __restrict__ Wz, const float* __restrict__ bz,
                 const float* __restrict__ Wr, const float* __restrict__ br,
                 const float* __restrict__ Wh, const float* __restrict__ bh,
                 float* __restrict__ out,
                 unsigned short* h_buf, unsigned short* rh_buf, uint32* flags)
{
  extern __shared__ char smem[];
  _Float16* A_l  = (_Float16*)(smem + LDS_A);
  _Float16* Wz_l = (_Float16*)(smem + LDS_WZ);
  _Float16* Wr_l = (_Float16*)(smem + LDS_WR);
  _Float16* Wh_l = (_Float16*)(smem + LDS_WH);
  float*    sc   = (float*)(smem + LDS_SC);

  const int tid  = threadIdx.x;
  const int g    = blockIdx.x & 7;
  const int rank = blockIdx.x >> 3;
  uint32* gf = flags + g * 64;                    // group flags padded to 256B
  unsigned short* hbG  = h_buf  + (size_t)g * BG * HSZ;
  unsigned short* rhbG = rh_buf + (size_t)g * BG * HSZ;

  // ---- one-time: weight slices -> LDS fp16 ----
  {
    const int r  = tid & 15;
    const int ch = tid >> 4;
    for (int mi = 0; mi < 3; ++mi) {
      const float* Ws = (mi == 0) ? Wz : (mi == 1 ? Wr : Wh);
      _Float16*    Ld = (mi == 0) ? Wz_l : (mi == 1 ? Wr_l : Wh_l);
      const float4* s = (const float4*)(Ws + (size_t)(rank * NC + r) * K1 + ch * 48);
      uint4* d = (uint4*)(Ld + r * LDK + ch * 48);
      #pragma unroll
      for (int j = 0; j < 6; ++j) {
        float4 v0 = s[2 * j], v1 = s[2 * j + 1];
        d[j] = make_uint4(f2x(v0.x, v0.y), f2x(v0.z, v0.w),
                          f2x(v1.x, v1.y), f2x(v1.z, v1.w));
      }
    }
  }

  // elementwise map: (batch bl, col cl)
  const int cl = tid & 15, bl = tid >> 4;
  // staging map: consecutive lanes -> consecutive rows (conflict-free b128 LDS stores)
  const int bl2 = tid & 15, cl2 = tid >> 4;
  const int cg = rank * NC + cl;
  const int bg = g * BG + bl;
  const int bg2 = g * BG + bl2;
  const float bz_r = bz[cg], br_r = br[cg], bh_r = bh[cg];

  float h_reg = 0.f, zg = 0.f;

  // prefetch x[0]: thread covers row bl2, I-cols cl2*16..+16
  float4 px0, px1, px2, px3;
  {
    const float4* xs = (const float4*)(x + (size_t)bg2 * ISZ + cl2 * 16);
    px0 = xs[0]; px1 = xs[1]; px2 = xs[2]; px3 = xs[3];
  }

  const int wv = tid >> 6, lane = tid & 63;
  const int mrow = lane & 15, q = lane >> 4;
  const int scO = bl * 17 + cl;

  for (int t = 0; t < T_STEPS; ++t) {
    // ---- S0: stage x_t into A[:, 512:768) ----
    {
      uint4* xd = (uint4*)(A_l + bl2 * LDK + HSZ + cl2 * 16);
      xd[0] = make_uint4(f2x(px0.x, px0.y), f2x(px0.z, px0.w),
                         f2x(px1.x, px1.y), f2x(px1.z, px1.w));
      xd[1] = make_uint4(f2x(px2.x, px2.y), f2x(px2.z, px2.w),
                         f2x(px3.x, px3.y), f2x(px3.z, px3.w));
    }
    __syncthreads();

    // ---- S1: exchange-independent x-part MFMAs, then poll h flags ----
    f32x4 acc1 = {0.f, 0.f, 0.f, 0.f};   // z (wv 0,1) or r (wv 2,3)
    f32x4 acc2 = {0.f, 0.f, 0.f, 0.f};   // cand partial
    {
      const _Float16* Wt = (wv < 2) ? Wz_l : Wr_l;
      const int kb1 = HSZ + (wv & 1) * 128;
      const half8* Ap = (const half8*)(A_l + mrow * LDK + kb1 + q * 8);
      const half8* Bp = (const half8*)(Wt  + mrow * LDK + kb1 + q * 8);
      #pragma unroll
      for (int kk = 0; kk < 4; ++kk)
        acc1 = __builtin_amdgcn_mfma_f32_16x16x32_f16(Ap[kk * 4], Bp[kk * 4], acc1, 0, 0, 0);
      const int kb2 = HSZ + wv * 64;
      const half8* Ap2 = (const half8*)(A_l  + mrow * LDK + kb2 + q * 8);
      const half8* Bp2 = (const half8*)(Wh_l + mrow * LDK + kb2 + q * 8);
      #pragma unroll
      for (int kk = 0; kk < 2; ++kk)
        acc2 = __builtin_amdgcn_mfma_f32_16x16x32_f16(Ap2[kk * 4], Bp2[kk * 4], acc2, 0, 0, 0);
    }
    if (tid < GC) {
      const uint32 need = (uint32)(2 * t);
      while (ALD(gf + tid) < need) {}
    }
    __syncthreads();

    // ---- S2: read h_{t-1} (sc1 loads) -> A[:, 0:512) ----
    {
      const uint64* hs = (const uint64*)(hbG + bl2 * HSZ + cl2 * 32);
      uint64 v0 = ALD(hs + 0), v1 = ALD(hs + 1), v2 = ALD(hs + 2), v3 = ALD(hs + 3);
      uint64 v4 = ALD(hs + 4), v5 = ALD(hs + 5), v6 = ALD(hs + 6), v7 = ALD(hs + 7);
      uint4* hd = (uint4*)(A_l + bl2 * LDK + cl2 * 32);
      hd[0] = make_uint4((uint32)v0, (uint32)(v0 >> 32), (uint32)v1, (uint32)(v1 >> 32));
      hd[1] = make_uint4((uint32)v2, (uint32)(v2 >> 32), (uint32)v3, (uint32)(v3 >> 32));
      hd[2] = make_uint4((uint32)v4, (uint32)(v4 >> 32), (uint32)v5, (uint32)(v5 >> 32));
      hd[3] = make_uint4((uint32)v6, (uint32)(v6 >> 32), (uint32)v7, (uint32)(v7 >> 32));
    }
    __syncthreads();

    // ---- S3: phase-1 h-part MFMAs ----
    {
      const _Float16* Wt = (wv < 2) ? Wz_l : Wr_l;
      const int kb = (wv & 1) * 256;
      const half8* Ap = (const half8*)(A_l + mrow * LDK + kb + q * 8);
      const half8* Bp = (const half8*)(Wt  + mrow * LDK + kb + q * 8);
      #pragma unroll
      for (int kk = 0; kk < 8; ++kk)
        acc1 = __builtin_amdgcn_mfma_f32_16x16x32_f16(Ap[kk * 4], Bp[kk * 4], acc1, 0, 0, 0);
      float* scw = sc + wv * 272;
      #pragma unroll
      for (int i = 0; i < 4; ++i) scw[(q * 4 + i) * 17 + mrow] = acc1[i];
    }
    __syncthreads();

    // ---- S4: z,r elementwise; publish rh (flag 2t+1) ----
    {
      float zp = sc[scO] + sc[272 + scO] + bz_r;
      float rp = sc[544 + scO] + sc[816 + scO] + br_r;
      zg = sigm(zp);
      float rhv = sigm(rp) * h_reg;
      __half hh = __float2half(rhv);
      uint32 lo = (uint32)__half_as_ushort(hh);
      uint32 hi = (uint32)__shfl_down((int)lo, 1);
      if (!(tid & 1))
        AST((uint32*)(rhbG + bl * HSZ + rank * NC + cl), lo | (hi << 16));
    }
    asm volatile("s_waitcnt vmcnt(0)" ::: "memory");
    __syncthreads();
    if (tid == 0) AST(gf + rank, (uint32)(2 * t + 1));

    // prefetch x[t+1] (overlaps rh wait + phase 2)
    if (t + 1 < T_STEPS) {
      const float4* xs = (const float4*)(x + ((size_t)(t + 1) * BSZ + bg2) * ISZ + cl2 * 16);
      px0 = xs[0]; px1 = xs[1]; px2 = xs[2]; px3 = xs[3];
    }

    // ---- S5: poll rh flags ----
    if (tid < GC) {
      const uint32 need = (uint32)(2 * t + 1);
      while (ALD(gf + tid) < need) {}
    }
    __syncthreads();

    // ---- S6: read rh (sc1) -> A[:, 0:512) ----
    {
      const uint64* rs = (const uint64*)(rhbG + bl2 * HSZ + cl2 * 32);
      uint64 v0 = ALD(rs + 0), v1 = ALD(rs + 1), v2 = ALD(rs + 2), v3 = ALD(rs + 3);
      uint64 v4 = ALD(rs + 4), v5 = ALD(rs + 5), v6 = ALD(rs + 6), v7 = ALD(rs + 7);
      uint4* rd = (uint4*)(A_l + bl2 * LDK + cl2 * 32);
      rd[0] = make_uint4((uint32)v0, (uint32)(v0 >> 32), (uint32)v1, (uint32)(v1 >> 32));
      rd[1] = make_uint4((uint32)v2, (uint32)(v2 >> 32), (uint32)v3, (uint32)(v3 >> 32));
      rd[2] = make_uint4((uint32)v4, (uint32)(v4 >> 32), (uint32)v5, (uint32)(v5 >> 32));
      rd[3] = make_uint4((uint32)v6, (uint32)(v6 >> 32), (uint32)v7, (uint32)(v7 >> 32));
    }
    __syncthreads();

    // ---- S7: phase-2 h-part MFMAs ----
    {
      const int kb = wv * 128;
      const half8* Ap = (const half8*)(A_l  + mrow * LDK + kb + q * 8);
      const half8* Bp = (const half8*)(Wh_l + mrow * LDK + kb + q * 8);
      #pragma unroll
      for (int kk = 0; kk < 4; ++kk)
        acc2 = __builtin_amdgcn_mfma_f32_16x16x32_f16(Ap[kk * 4], Bp[kk * 4], acc2, 0, 0, 0);
      float* scw = sc + wv * 272;
      #pragma unroll
      for (int i = 0; i < 4; ++i) scw[(q * 4 + i) * 17 + mrow] = acc2[i];
    }
    __syncthreads();

    // ---- S8: cand, h update, out store, publish h (flag 2t+2) ----
    {
      float cp = sc[scO] + sc[272 + scO] + sc[544 + scO] + sc[816 + scO] + bh_r;
      float cand = tanhx(cp);
      float hn = (1.f - zg) * h_reg + zg * cand;
      h_reg = hn;
      out[((size_t)t * BSZ + bg) * HSZ + cg] = hn;
      if (t == T_STEPS - 1)
        out[((size_t)T_STEPS * BSZ + bg) * HSZ + cg] = hn;   // h_last
      __half hh = __float2half(hn);
      uint32 lo = (uint32)__half_as_ushort(hh);
      uint32 hi = (uint32)__shfl_down((int)lo, 1);
      if (!(tid & 1))
        AST((uint32*)(hbG + bl * HSZ + rank * NC + cl), lo | (hi << 16));
    }
    asm volatile("s_waitcnt vmcnt(0)" ::: "memory");
    __syncthreads();
    if (tid == 0) AST(gf + rank, (uint32)(2 * t + 2));
  }
}

extern "C" void kernel_launch(void* const* d_in, const int* in_sizes, int n_in,
                              void* d_out, int out_size, void* d_ws, size_t ws_size,
                              hipStream_t stream) {
  const float* x  = (const float*)d_in[0];
  const float* Wz = (const float*)d_in[1];
  const float* bz = (const float*)d_in[2];
  const float* Wr = (const float*)d_in[3];
  const float* br = (const float*)d_in[4];
  const float* Wh = (const float*)d_in[5];
  const float* bh = (const float*)d_in[6];
  float* out = (float*)d_out;

  // ws layout: [flags 8*64 u32 = 2KB][h_buf 128KB][rh_buf 128KB]
  uint32* flags = (uint32*)d_ws;
  unsigned short* h_buf  = (unsigned short*)((char*)d_ws + 2048);
  unsigned short* rh_buf = h_buf + NG * BG * HSZ;

  // zero flags + h0 (rh_buf is written before first read; no clear needed)
  hipMemsetAsync(d_ws, 0, 2048 + (size_t)NG * BG * HSZ * 2, stream);

  hipFuncSetAttribute(reinterpret_cast<const void*>(gru_persist),
                      hipFuncAttributeMaxDynamicSharedMemorySize, SMEM_BYTES);

  hipLaunchKernelGGL(gru_persist, dim3(NG * GC), dim3(256), SMEM_BYTES, stream,
                     x, Wz, bz, Wr, br, Wh, bh, out, h_buf, rh_buf, flags);
}